// Round 5
// baseline (1030.202 us; speedup 1.0000x reference)
//
#include <hip/hip_runtime.h>

// MoE FFN top-2/8. R5: 8-phase 256x256 8-wave GEMMs (T3+T4 counted vmcnt,
// T5 setprio, T2 via pre-swizzled source), gate/up folded into one B operand
// (16-col interleave), down K-split=2, XCD-clustered compacted grids.

#define DM 1024
#define DI 4096
#define NE 8
#define TOK 8192
#define MAXPE 8192
#define NT2 72               // >= sum ceil(ne/256) = 72 worst case

typedef __attribute__((ext_vector_type(4))) float f32x4;
typedef __attribute__((ext_vector_type(8))) short bf16x8;
typedef __attribute__((ext_vector_type(8))) unsigned short u16x8;

#define MFMA(a, b, c) __builtin_amdgcn_mfma_f32_16x16x32_bf16(a, b, c, 0, 0, 0)
#define GLDS16(g, l) __builtin_amdgcn_global_load_lds( \
    (const __attribute__((address_space(1))) unsigned int*)(g), \
    (__attribute__((address_space(3))) unsigned int*)(l), 16, 0, 0)

__device__ __forceinline__ unsigned short bf16_rn(float f) {
    unsigned int u = __builtin_bit_cast(unsigned int, f);
    u += 0x7fffu + ((u >> 16) & 1u);
    return (unsigned short)(u >> 16);
}

// ---------------------------------------------------------------------------
// Router (numerics frozen since R1).
// ---------------------------------------------------------------------------
__global__ __launch_bounds__(256) void router_kernel(
    const float* __restrict__ x, const float* __restrict__ rw,
    const float* __restrict__ rb,
    int* __restrict__ counts, int* __restrict__ tok_list,
    float* __restrict__ w_list)
{
    int t = blockIdx.x * 4 + (threadIdx.x >> 6);
    int lane = threadIdx.x & 63;
    const float* xr = x + (size_t)t * DM;
    float acc[NE];
#pragma unroll
    for (int e = 0; e < NE; ++e) acc[e] = 0.f;
    for (int i = lane; i < DM; i += 64) {
        float xv = xr[i];
#pragma unroll
        for (int e = 0; e < NE; ++e) acc[e] += xv * rw[e * DM + i];
    }
#pragma unroll
    for (int e = 0; e < NE; ++e) {
        float v = acc[e];
#pragma unroll
        for (int s = 32; s >= 1; s >>= 1) v += __shfl_xor(v, s, 64);
        acc[e] = v;
    }
    if (lane == 0) {
        float l0 = -3.4e38f, l1 = -3.4e38f;
        int i0 = 0, i1 = 0;
#pragma unroll
        for (int e = 0; e < NE; ++e) {
            float v = acc[e] + rb[e];
            if (v > l0) { l1 = l0; i1 = i0; l0 = v; i0 = e; }
            else if (v > l1) { l1 = v; i1 = e; }
        }
        float z = expf(l1 - l0);
        float w0 = 1.f / (1.f + z);
        float w1 = z / (1.f + z);
        int p0 = atomicAdd(&counts[i0], 1);
        tok_list[i0 * MAXPE + p0] = t; w_list[i0 * MAXPE + p0] = w0;
        int p1 = atomicAdd(&counts[i1], 1);
        tok_list[i1 * MAXPE + p1] = t; w_list[i1 * MAXPE + p1] = w1;
    }
}

// Prefix offsets + compact (expert, 256-row-tile) table, sentinel-padded.
__global__ void scan_kernel(const int* __restrict__ counts,
                            int* __restrict__ offs, int* __restrict__ tiles2) {
    if (threadIdx.x == 0) {
        int s = 0, nt = 0;
        for (int e = 0; e < NE; ++e) { offs[e] = s; s += counts[e]; }
        for (int e = 0; e < NE; ++e) {
            int nmb = (counts[e] + 255) / 256;
            for (int mb = 0; mb < nmb && nt < NT2; ++mb)
                tiles2[nt++] = (e << 16) | mb;
        }
        for (; nt < NT2; ++nt) tiles2[nt] = -1;
    }
}

// ---------------------------------------------------------------------------
// f32 -> bf16 conversion, 8 elems/thread, optional per-expert source stride.
// ---------------------------------------------------------------------------
__global__ __launch_bounds__(256) void conv_kernel(
    const float* __restrict__ src, unsigned short* __restrict__ dst,
    long total, int shift, long estride)
{
    long i8 = ((long)blockIdx.x * 256 + threadIdx.x) * 8;
    if (i8 >= total) return;
    long e = i8 >> shift;
    long r = i8 - (e << shift);
    const float* s = src + e * estride + r;
    f32x4 a = *(const f32x4*)s;
    f32x4 b = *(const f32x4*)(s + 4);
    u16x8 o;
#pragma unroll
    for (int j = 0; j < 4; ++j) { o[j] = bf16_rn(a[j]); o[4 + j] = bf16_rn(b[j]); }
    *(u16x8*)(dst + i8) = o;
}

// ---------------------------------------------------------------------------
// 8-phase machinery (shared by both GEMMs via macros).
// LDS: ldsA/ldsB [buf=tile&1][half][128 rows x 64 cols bf16] = 32KB each arr
// dim -> total 128KB. Halves: A by (row>>6)&1 (64-row bands), B by (col>>5)&1
// (32-col bands) so all waves consume the same half in a given phase.
// ---------------------------------------------------------------------------
#define STAGEX(LDS_, SRC0_, SRC1_, H_, ST_) do { if ((ST_) < NKT) { \
    GLDS16((SRC0_) + (size_t)(ST_) * 64, &LDS_[(ST_) & 1][H_][w * 512]); \
    GLDS16((SRC1_) + (size_t)(ST_) * 64, &LDS_[(ST_) & 1][H_][(8 + w) * 512]); } } while (0)

#define PHASE(BUFI, RH, CH, STMT) do { \
    bf16x8 a_[4][2], b_[2][2]; \
    _Pragma("unroll") for (int mf = 0; mf < 4; ++mf) \
    _Pragma("unroll") for (int kk = 0; kk < 2; ++kk) \
        a_[mf][kk] = *(const bf16x8*)((const char*)&ldsA[BUFI][RH][0] + \
            (wm * 64 + mf * 16 + lr) * 128 + ((kk * 64 + lk * 16) ^ xsw)); \
    _Pragma("unroll") for (int nf = 0; nf < 2; ++nf) \
    _Pragma("unroll") for (int kk = 0; kk < 2; ++kk) \
        b_[nf][kk] = *(const bf16x8*)((const char*)&ldsB[BUFI][CH][0] + \
            (wn * 32 + nf * 16 + lr) * 128 + ((kk * 64 + lk * 16) ^ xsw)); \
    STMT; \
    __builtin_amdgcn_sched_barrier(0); \
    __builtin_amdgcn_s_barrier(); \
    asm volatile("s_waitcnt lgkmcnt(0)" ::: "memory"); \
    __builtin_amdgcn_sched_barrier(0); \
    __builtin_amdgcn_s_setprio(1); \
    _Pragma("unroll") for (int mf = 0; mf < 4; ++mf) \
    _Pragma("unroll") for (int nf = 0; nf < 2; ++nf) \
    _Pragma("unroll") for (int kk = 0; kk < 2; ++kk) \
        acc[(RH) * 4 + mf][(CH) * 2 + nf] = \
            MFMA(a_[mf][kk], b_[nf][kk], acc[(RH) * 4 + mf][(CH) * 2 + nf]); \
    __builtin_amdgcn_s_setprio(0); \
    __builtin_amdgcn_sched_barrier(0); \
    __builtin_amdgcn_s_barrier(); \
} while (0)

#define VMW4 do { asm volatile("s_waitcnt vmcnt(4)" ::: "memory"); \
                  __builtin_amdgcn_sched_barrier(0); } while (0)

// ---------------------------------------------------------------------------
// Gate+Up GEMM, 8-phase. Output tile: 256 tokens x 256 B-rows, where B-rows
// interleave gate/up at 16-col granularity ((br>>4)&1: 0=gate,1=up) so the
// silu(g)*u pair is thread-local (nf parity). K = DM = 1024.
// ---------------------------------------------------------------------------
__global__ __launch_bounds__(512, 2) void gateup8(
    const unsigned short* __restrict__ xb,
    const unsigned short* __restrict__ gwb,   // [NE][CHC][DM] bf16 slice
    const unsigned short* __restrict__ uwb,
    const int* __restrict__ counts, const int* __restrict__ offs,
    const int* __restrict__ tiles2, const int* __restrict__ tok_list,
    unsigned short* __restrict__ H, int cb, int CHC)
{
    const int tx = ((blockIdx.x & 7) * 9) + (blockIdx.x >> 3);  // XCD cluster
    const int pk = tiles2[tx];
    if (pk < 0) return;
    const int e = pk >> 16, tile = pk & 0xffff;
    const int ne = counts[e];
    const int by = blockIdx.y;                 // 256 B-rows of 2*CHC
    const int tid = threadIdx.x, lane = tid & 63, w = tid >> 6;
    const int lr = lane & 15, lk = lane >> 4;
    const int wm = w >> 2, wn = w & 3;
    const int xsw = (lr & 7) << 4;
    const int NKT = DM / 64;                   // 16
    const int NIT = NKT / 2;                   // 8

    __shared__ __align__(16) unsigned short ldsA[2][2][8192];  // 64KB
    __shared__ __align__(16) unsigned short ldsB[2][2][8192];  // 64KB

    // ---- per-thread staging source pointers (constant over K) ----
    const unsigned short* sA[2][2];            // [q][h]
    const unsigned short* sB[2][2];
#pragma unroll
    for (int q = 0; q < 2; ++q)
#pragma unroll
        for (int h = 0; h < 2; ++h) {
            int bi = q * 8 + w;
            int l8 = bi * 8 + (lane >> 3);                     // 0..127
            int scol = (((lane & 7) ^ (l8 & 7)) << 3);
            // A: token rows, halves = 64-row bands
            int R = ((l8 >> 6) << 7) | (h << 6) | (l8 & 63);
            int rg = tile * 256 + R;
            int rc = rg < ne ? rg : ne - 1;
            int tok = tok_list[e * MAXPE + rc];
            sA[q][h] = xb + (size_t)tok * DM + scol;
            // B: interleaved gate/up rows, halves = 32-col bands
            int cc = ((l8 >> 5) << 6) | (h << 5) | (l8 & 31);  // 0..255
            int br = by * 256 + cc;                            // 0..2*CHC-1
            int mat = (cc >> 4) & 1;
            int wrow = ((br >> 5) << 4) + (br & 15);           // 0..CHC-1
            const unsigned short* pB = mat ? uwb : gwb;
            sB[q][h] = pB + ((size_t)e * CHC + wrow) * DM + scol;
        }

    f32x4 acc[8][4];
#pragma unroll
    for (int m = 0; m < 8; ++m)
#pragma unroll
        for (int n = 0; n < 4; ++n) acc[m][n] = (f32x4)0.f;

    // ---- prologue: t0 all 4 halves + t1 A0,B0 ----
    STAGEX(ldsA, sA[0][0], sA[1][0], 0, 0);
    STAGEX(ldsB, sB[0][0], sB[1][0], 0, 0);
    STAGEX(ldsA, sA[0][1], sA[1][1], 1, 0);
    STAGEX(ldsB, sB[0][1], sB[1][1], 1, 0);
    STAGEX(ldsA, sA[0][0], sA[1][0], 0, 1);
    STAGEX(ldsB, sB[0][0], sB[1][0], 0, 1);
    VMW4;
    __builtin_amdgcn_s_barrier();

#pragma unroll 1
    for (int i = 0; i < NIT; ++i) {
        const int t1 = 2 * i + 1;
        PHASE(0, 0, 0, STAGEX(ldsA, sA[0][1], sA[1][1], 1, t1));      // Y.A1
        PHASE(0, 0, 1, STAGEX(ldsB, sB[0][1], sB[1][1], 1, t1));      // Y.B1
        PHASE(0, 1, 0, STAGEX(ldsA, sA[0][0], sA[1][0], 0, t1 + 1));  // X'.A0
        PHASE(0, 1, 1, STAGEX(ldsB, sB[0][0], sB[1][0], 0, t1 + 1));  // X'.B0
        VMW4;
        PHASE(1, 0, 0, STAGEX(ldsA, sA[0][1], sA[1][1], 1, t1 + 1));  // X'.A1
        PHASE(1, 0, 1, STAGEX(ldsB, sB[0][1], sB[1][1], 1, t1 + 1));  // X'.B1
        PHASE(1, 1, 0, STAGEX(ldsA, sA[0][0], sA[1][0], 0, t1 + 2));  // Y'.A0
        PHASE(1, 1, 1, STAGEX(ldsB, sB[0][0], sB[1][0], 0, t1 + 2));  // Y'.B0
        VMW4;
    }

    // ---- epilogue: silu(g)*u -> H ----
    const int hrow0 = offs[e] + tile * 256;
#pragma unroll
    for (int am = 0; am < 8; ++am)
#pragma unroll
        for (int j = 0; j < 4; ++j) {
            int R = wm * 128 + (am >> 2) * 64 + (am & 3) * 16 + lk * 4 + j;
            if (tile * 256 + R < ne) {
#pragma unroll
                for (int ch = 0; ch < 2; ++ch) {
                    float g = acc[am][ch * 2 + 0][j];
                    float u = acc[am][ch * 2 + 1][j];
                    float hv = (g / (1.f + expf(-g))) * u;
                    int brb = by * 256 + wn * 64 + ch * 32 + lr;
                    int hcol = cb + ((brb >> 5) << 4) + (brb & 15);
                    H[(size_t)(hrow0 + R) * DI + hcol] = bf16_rn(hv);
                }
            }
        }
}

// ---------------------------------------------------------------------------
// Down GEMM, 8-phase. 256 H-rows x 256 out-cols, K-split=2 (kq in {0,1},
// K=2048 each). Weighted atomicAdd scatter.
// ---------------------------------------------------------------------------
__global__ __launch_bounds__(512, 2) void down8(
    const unsigned short* __restrict__ dwb,   // [NE][DM][DI] bf16
    const int* __restrict__ counts, const int* __restrict__ offs,
    const int* __restrict__ tiles2, const int* __restrict__ tok_list,
    const float* __restrict__ w_list,
    const unsigned short* __restrict__ H,
    float* __restrict__ out)
{
    const int tx = ((blockIdx.x & 7) * 9) + (blockIdx.x >> 3);  // XCD cluster
    const int pk = tiles2[tx];
    if (pk < 0) return;
    const int e = pk >> 16, tile = pk & 0xffff;
    const int ne = counts[e];
    const int by = blockIdx.y >> 1;            // 0..3 (256-col group of DM)
    const int kq = blockIdx.y & 1;             // K-split half
    const int tid = threadIdx.x, lane = tid & 63, w = tid >> 6;
    const int lr = lane & 15, lk = lane >> 4;
    const int wm = w >> 2, wn = w & 3;
    const int xsw = (lr & 7) << 4;
    const int NKT = (DI / 2) / 64;             // 32
    const int NIT = NKT / 2;                   // 16
    const int kbase = kq * (DI / 2);

    __shared__ __align__(16) unsigned short ldsA[2][2][8192];
    __shared__ __align__(16) unsigned short ldsB[2][2][8192];

    const int hrow0 = offs[e] + tile * 256;
    const unsigned short* sA[2][2];
    const unsigned short* sB[2][2];
#pragma unroll
    for (int q = 0; q < 2; ++q)
#pragma unroll
        for (int h = 0; h < 2; ++h) {
            int bi = q * 8 + w;
            int l8 = bi * 8 + (lane >> 3);
            int scol = (((lane & 7) ^ (l8 & 7)) << 3);
            int R = ((l8 >> 6) << 7) | (h << 6) | (l8 & 63);
            sA[q][h] = H + (size_t)(hrow0 + R) * DI + kbase + scol;  // pad-safe
            int cc = ((l8 >> 5) << 6) | (h << 5) | (l8 & 31);
            sB[q][h] = dwb + ((size_t)e * DM + by * 256 + cc) * DI + kbase + scol;
        }

    f32x4 acc[8][4];
#pragma unroll
    for (int m = 0; m < 8; ++m)
#pragma unroll
        for (int n = 0; n < 4; ++n) acc[m][n] = (f32x4)0.f;

    STAGEX(ldsA, sA[0][0], sA[1][0], 0, 0);
    STAGEX(ldsB, sB[0][0], sB[1][0], 0, 0);
    STAGEX(ldsA, sA[0][1], sA[1][1], 1, 0);
    STAGEX(ldsB, sB[0][1], sB[1][1], 1, 0);
    STAGEX(ldsA, sA[0][0], sA[1][0], 0, 1);
    STAGEX(ldsB, sB[0][0], sB[1][0], 0, 1);
    VMW4;
    __builtin_amdgcn_s_barrier();

#pragma unroll 1
    for (int i = 0; i < NIT; ++i) {
        const int t1 = 2 * i + 1;
        PHASE(0, 0, 0, STAGEX(ldsA, sA[0][1], sA[1][1], 1, t1));
        PHASE(0, 0, 1, STAGEX(ldsB, sB[0][1], sB[1][1], 1, t1));
        PHASE(0, 1, 0, STAGEX(ldsA, sA[0][0], sA[1][0], 0, t1 + 1));
        PHASE(0, 1, 1, STAGEX(ldsB, sB[0][0], sB[1][0], 0, t1 + 1));
        VMW4;
        PHASE(1, 0, 0, STAGEX(ldsA, sA[0][1], sA[1][1], 1, t1 + 1));
        PHASE(1, 0, 1, STAGEX(ldsB, sB[0][1], sB[1][1], 1, t1 + 1));
        PHASE(1, 1, 0, STAGEX(ldsA, sA[0][0], sA[1][0], 0, t1 + 2));
        PHASE(1, 1, 1, STAGEX(ldsB, sB[0][0], sB[1][0], 0, t1 + 2));
        VMW4;
    }

    // ---- epilogue: weighted atomic scatter ----
#pragma unroll
    for (int am = 0; am < 8; ++am)
#pragma unroll
        for (int j = 0; j < 4; ++j) {
            int R = wm * 128 + (am >> 2) * 64 + (am & 3) * 16 + lk * 4 + j;
            int grow = tile * 256 + R;
            if (grow < ne) {
                int t = tok_list[e * MAXPE + grow];
                float wgt = w_list[e * MAXPE + grow];
#pragma unroll
                for (int an = 0; an < 4; ++an) {
                    int c = by * 256 + wn * 64 + (an >> 1) * 32 + (an & 1) * 16 + lr;
                    atomicAdd(&out[(size_t)t * DM + c], wgt * acc[am][an][j]);
                }
            }
        }
}

// ---------------------------------------------------------------------------
extern "C" void kernel_launch(void* const* d_in, const int* in_sizes, int n_in,
                              void* d_out, int out_size, void* d_ws, size_t ws_size,
                              hipStream_t stream) {
    const float* x = (const float*)d_in[0];
    const float* router_w = (const float*)d_in[1];
    const float* router_b = (const float*)d_in[2];
    const float* gate_w = (const float*)d_in[3];
    const float* up_w = (const float*)d_in[4];
    const float* down_w = (const float*)d_in[5];
    float* out = (float*)d_out;

    char* ws = (char*)d_ws;
    int* counts = (int*)ws;                              // +0
    int* offs = (int*)(ws + 64);                         // +64
    int* tiles2 = (int*)(ws + 128);                      // 72 ints
    int* tok_list = (int*)(ws + 512);
    float* w_list = (float*)(ws + 512 + (size_t)NE * MAXPE * 4);
    size_t off = 512 + (size_t)NE * MAXPE * 8;
    off = (off + 255) & ~(size_t)255;

    unsigned short* xb = (unsigned short*)(ws + off);  off += (size_t)TOK * DM * 2;
    unsigned short* dwb = (unsigned short*)(ws + off); off += (size_t)NE * DM * DI * 2;
    unsigned short* H = (unsigned short*)(ws + off);   off += (size_t)(2 * TOK + 256) * DI * 2;

    int CHC = 128;
    for (int c = 2048; c >= 128; c >>= 1)
        if (off + (size_t)2 * NE * c * DM * 2 <= ws_size) { CHC = c; break; }
    unsigned short* gwb = (unsigned short*)(ws + off);
    unsigned short* uwb = gwb + (size_t)NE * CHC * DM;

    hipMemsetAsync(out, 0, (size_t)out_size * sizeof(float), stream);
    hipMemsetAsync(counts, 0, NE * sizeof(int), stream);

    router_kernel<<<TOK / 4, 256, 0, stream>>>(x, router_w, router_b,
                                               counts, tok_list, w_list);
    scan_kernel<<<1, 64, 0, stream>>>(counts, offs, tiles2);

    conv_kernel<<<(TOK * DM) / 2048, 256, 0, stream>>>(
        x, xb, (long)TOK * DM, 23, 0);
    conv_kernel<<<(int)(((long)NE * DM * DI) / 2048), 256, 0, stream>>>(
        down_w, dwb, (long)NE * DM * DI, 25, 0);

    const int sh = 10 + __builtin_ctz((unsigned)CHC);   // log2(CHC*DM)
    for (int cb = 0; cb < DI; cb += CHC) {
        long tot = (long)NE * CHC * DM;
        conv_kernel<<<(int)(tot / 2048), 256, 0, stream>>>(
            gate_w + (size_t)cb * DM, gwb, tot, sh, (long)DI * DM);
        conv_kernel<<<(int)(tot / 2048), 256, 0, stream>>>(
            up_w + (size_t)cb * DM, uwb, tot, sh, (long)DI * DM);
        gateup8<<<dim3(NT2, 2 * CHC / 256), 512, 0, stream>>>(
            xb, gwb, uwb, counts, offs, tiles2, tok_list, H, cb, CHC);
    }
    down8<<<dim3(NT2, 8), 512, 0, stream>>>(
        dwb, counts, offs, tiles2, tok_list, w_list, H, out);
}

// Round 8
// 946.484 us; speedup vs baseline: 1.0885x; 1.0885x over previous
//
#include <hip/hip_runtime.h>

// MoE FFN top-2/8. R8: 8-phase register-reuse GEMMs. R7's vmcnt-before-
// barrier ordering PLUS the tail fix: STAGEX is now count-uniform (ST>=NKT
// wraps the SOURCE to K-tile 0, same 2 loads, same buffer target), so the
// vmcnt(4) ledger holds in EVERY iteration incl. the last (R6/R7's tail
// skipped SG3/SG4, leaving SG1/SG2 in flight when the final quad read them).

#define DM 1024
#define DI 4096
#define NE 8
#define TOK 8192
#define MAXPE 8192
#define NT2 72               // >= sum ceil(ne/256) = 72 worst case

typedef __attribute__((ext_vector_type(4))) float f32x4;
typedef __attribute__((ext_vector_type(8))) short bf16x8;
typedef __attribute__((ext_vector_type(8))) unsigned short u16x8;

#define MFMA(a, b, c) __builtin_amdgcn_mfma_f32_16x16x32_bf16(a, b, c, 0, 0, 0)
#define GLDS16(g, l) __builtin_amdgcn_global_load_lds( \
    (const __attribute__((address_space(1))) unsigned int*)(g), \
    (__attribute__((address_space(3))) unsigned int*)(l), 16, 0, 0)

__device__ __forceinline__ unsigned short bf16_rn(float f) {
    unsigned int u = __builtin_bit_cast(unsigned int, f);
    u += 0x7fffu + ((u >> 16) & 1u);
    return (unsigned short)(u >> 16);
}

// ---------------------------------------------------------------------------
// Router (numerics frozen since R1).
// ---------------------------------------------------------------------------
__global__ __launch_bounds__(256) void router_kernel(
    const float* __restrict__ x, const float* __restrict__ rw,
    const float* __restrict__ rb,
    int* __restrict__ counts, int* __restrict__ tok_list,
    float* __restrict__ w_list)
{
    int t = blockIdx.x * 4 + (threadIdx.x >> 6);
    int lane = threadIdx.x & 63;
    const float* xr = x + (size_t)t * DM;
    float acc[NE];
#pragma unroll
    for (int e = 0; e < NE; ++e) acc[e] = 0.f;
    for (int i = lane; i < DM; i += 64) {
        float xv = xr[i];
#pragma unroll
        for (int e = 0; e < NE; ++e) acc[e] += xv * rw[e * DM + i];
    }
#pragma unroll
    for (int e = 0; e < NE; ++e) {
        float v = acc[e];
#pragma unroll
        for (int s = 32; s >= 1; s >>= 1) v += __shfl_xor(v, s, 64);
        acc[e] = v;
    }
    if (lane == 0) {
        float l0 = -3.4e38f, l1 = -3.4e38f;
        int i0 = 0, i1 = 0;
#pragma unroll
        for (int e = 0; e < NE; ++e) {
            float v = acc[e] + rb[e];
            if (v > l0) { l1 = l0; i1 = i0; l0 = v; i0 = e; }
            else if (v > l1) { l1 = v; i1 = e; }
        }
        float z = expf(l1 - l0);
        float w0 = 1.f / (1.f + z);
        float w1 = z / (1.f + z);
        int p0 = atomicAdd(&counts[i0], 1);
        tok_list[i0 * MAXPE + p0] = t; w_list[i0 * MAXPE + p0] = w0;
        int p1 = atomicAdd(&counts[i1], 1);
        tok_list[i1 * MAXPE + p1] = t; w_list[i1 * MAXPE + p1] = w1;
    }
}

// Prefix offsets + compact (expert, 256-row-tile) table, sentinel-padded.
__global__ void scan_kernel(const int* __restrict__ counts,
                            int* __restrict__ offs, int* __restrict__ tiles2) {
    if (threadIdx.x == 0) {
        int s = 0, nt = 0;
        for (int e = 0; e < NE; ++e) { offs[e] = s; s += counts[e]; }
        for (int e = 0; e < NE; ++e) {
            int nmb = (counts[e] + 255) / 256;
            for (int mb = 0; mb < nmb && nt < NT2; ++mb)
                tiles2[nt++] = (e << 16) | mb;
        }
        for (; nt < NT2; ++nt) tiles2[nt] = -1;
    }
}

// ---------------------------------------------------------------------------
// f32 -> bf16 conversion, 8 elems/thread, optional per-expert source stride.
// ---------------------------------------------------------------------------
__global__ __launch_bounds__(256) void conv_kernel(
    const float* __restrict__ src, unsigned short* __restrict__ dst,
    long total, int shift, long estride)
{
    long i8 = ((long)blockIdx.x * 256 + threadIdx.x) * 8;
    if (i8 >= total) return;
    long e = i8 >> shift;
    long r = i8 - (e << shift);
    const float* s = src + e * estride + r;
    f32x4 a = *(const f32x4*)s;
    f32x4 b = *(const f32x4*)(s + 4);
    u16x8 o;
#pragma unroll
    for (int j = 0; j < 4; ++j) { o[j] = bf16_rn(a[j]); o[4 + j] = bf16_rn(b[j]); }
    *(u16x8*)(dst + i8) = o;
}

// ---------------------------------------------------------------------------
// 8-phase machinery. LDS: ldsA/ldsB[buf][half][128x64 bf16] (128KB total).
// A halves = 64-row token bands; B halves = 32-col bands. Per-buffer phase
// order (RH,CH): (0,0)->(0,1)->(1,1)->(1,0); ds_reads: 12/4/8/0 (reg reuse).
// INVARIANTS: (1) vmcnt(4) BEFORE the quad-end s_barrier (cross-wave
// completeness at the rendezvous); (2) STAGEX count-uniform: ST>=NKT wraps
// the SOURCE offset to 0 but still issues both loads to the ST&1 buffer,
// so "newest 4 outstanding" is ALWAYS this quad's SG3/SG4 — incl. the tail.
// ---------------------------------------------------------------------------
#define STAGEX(LDS_, SRC0_, SRC1_, H_, ST_) do { \
    size_t o_ = (size_t)(((ST_) < NKT) ? (ST_) : 0) * 64; \
    GLDS16((SRC0_) + o_, &LDS_[(ST_) & 1][H_][w * 512]); \
    GLDS16((SRC1_) + o_, &LDS_[(ST_) & 1][H_][(8 + w) * 512]); } while (0)

#define DSA(DST_, BUFI, RH) \
    _Pragma("unroll") for (int mf = 0; mf < 4; ++mf) \
    _Pragma("unroll") for (int kk = 0; kk < 2; ++kk) \
        DST_[mf][kk] = *(const bf16x8*)((const char*)&ldsA[BUFI][RH][0] + \
            (wm * 64 + mf * 16 + lr) * 128 + ((kk * 64 + lk * 16) ^ xsw));

#define DSB(DST_, BUFI, CH) \
    _Pragma("unroll") for (int nf = 0; nf < 2; ++nf) \
    _Pragma("unroll") for (int kk = 0; kk < 2; ++kk) \
        DST_[nf][kk] = *(const bf16x8*)((const char*)&ldsB[BUFI][CH][0] + \
            (wn * 32 + nf * 16 + lr) * 128 + ((kk * 64 + lk * 16) ^ xsw));

#define MFMAQ(AR_, BR_, RH, CH) do { \
    __builtin_amdgcn_s_setprio(1); \
    _Pragma("unroll") for (int mf = 0; mf < 4; ++mf) \
    _Pragma("unroll") for (int nf = 0; nf < 2; ++nf) \
    _Pragma("unroll") for (int kk = 0; kk < 2; ++kk) \
        acc[(RH) * 4 + mf][(CH) * 2 + nf] = \
            MFMA(AR_[mf][kk], BR_[nf][kk], acc[(RH) * 4 + mf][(CH) * 2 + nf]); \
    __builtin_amdgcn_s_setprio(0); \
} while (0)

// barrier + wait own ds_reads (phases with reads)
#define BARW do { __builtin_amdgcn_sched_barrier(0); __builtin_amdgcn_s_barrier(); \
    asm volatile("s_waitcnt lgkmcnt(0)" ::: "memory"); \
    __builtin_amdgcn_sched_barrier(0); } while (0)
// barrier only (no reads this phase / end of phase)
#define BARE do { __builtin_amdgcn_sched_barrier(0); __builtin_amdgcn_s_barrier(); \
    __builtin_amdgcn_sched_barrier(0); } while (0)

#define VMW4 do { asm volatile("s_waitcnt vmcnt(4)" ::: "memory"); \
                  __builtin_amdgcn_sched_barrier(0); } while (0)

// One buffer's 4 phases. Phase 4: MFMA, then vmcnt(4), THEN quad-end barrier.
#define QUAD(BUFI, SG1, SG2, SG3, SG4) do { \
    DSA(ar, BUFI, 0); DSB(b0r, BUFI, 0); \
    SG1; BARW; MFMAQ(ar, b0r, 0, 0); BARE; \
    DSB(b1r, BUFI, 1); \
    SG2; BARW; MFMAQ(ar, b1r, 0, 1); BARE; \
    DSA(ar, BUFI, 1); \
    SG3; BARW; MFMAQ(ar, b1r, 1, 1); BARE; \
    SG4; BARE; MFMAQ(ar, b0r, 1, 0); VMW4; BARE; \
} while (0)

// ---------------------------------------------------------------------------
// Gate+Up GEMM, 8-phase. 256 tokens x 256 B-rows (gate/up interleaved at
// 16-col granularity), K = DM = 1024.
// ---------------------------------------------------------------------------
__global__ __launch_bounds__(512, 2) void gateup9(
    const unsigned short* __restrict__ xb,
    const unsigned short* __restrict__ gwb,   // [NE][CHC][DM] bf16 slice
    const unsigned short* __restrict__ uwb,
    const int* __restrict__ counts, const int* __restrict__ offs,
    const int* __restrict__ tiles2, const int* __restrict__ tok_list,
    unsigned short* __restrict__ H, int cb, int CHC)
{
    const int tx = ((blockIdx.x & 7) * 9) + (blockIdx.x >> 3);  // XCD cluster
    const int pk = tiles2[tx];
    if (pk < 0) return;
    const int e = pk >> 16, tile = pk & 0xffff;
    const int ne = counts[e];
    const int by = blockIdx.y;
    const int tid = threadIdx.x, lane = tid & 63, w = tid >> 6;
    const int lr = lane & 15, lk = lane >> 4;
    const int wm = w >> 2, wn = w & 3;
    const int xsw = (lr & 7) << 4;
    const int NKT = DM / 64;                   // 16
    const int NIT = NKT / 2;                   // 8

    __shared__ __align__(16) unsigned short ldsA[2][2][8192];  // 64KB
    __shared__ __align__(16) unsigned short ldsB[2][2][8192];  // 64KB

    const unsigned short* sA[2][2];
    const unsigned short* sB[2][2];
#pragma unroll
    for (int q = 0; q < 2; ++q)
#pragma unroll
        for (int h = 0; h < 2; ++h) {
            int bi = q * 8 + w;
            int l8 = bi * 8 + (lane >> 3);                     // 0..127
            int scol = (((lane & 7) ^ (l8 & 7)) << 3);
            int R = ((l8 >> 6) << 7) | (h << 6) | (l8 & 63);
            int rg = tile * 256 + R;
            int rc = rg < ne ? rg : ne - 1;
            int tok = tok_list[e * MAXPE + rc];
            sA[q][h] = xb + (size_t)tok * DM + scol;
            int cc = ((l8 >> 5) << 6) | (h << 5) | (l8 & 31);  // 0..255
            int br = by * 256 + cc;
            int mat = (cc >> 4) & 1;
            int wrow = ((br >> 5) << 4) + (br & 15);
            const unsigned short* pB = mat ? uwb : gwb;
            sB[q][h] = pB + ((size_t)e * CHC + wrow) * DM + scol;
        }

    f32x4 acc[8][4];
#pragma unroll
    for (int m = 0; m < 8; ++m)
#pragma unroll
        for (int n = 0; n < 4; ++n) acc[m][n] = (f32x4)0.f;

    bf16x8 ar[4][2], b0r[2][2], b1r[2][2];

    // prologue: t0 all 4 halves + t1 h0; vmcnt THEN barrier
    STAGEX(ldsA, sA[0][0], sA[1][0], 0, 0);
    STAGEX(ldsB, sB[0][0], sB[1][0], 0, 0);
    STAGEX(ldsA, sA[0][1], sA[1][1], 1, 0);
    STAGEX(ldsB, sB[0][1], sB[1][1], 1, 0);
    STAGEX(ldsA, sA[0][0], sA[1][0], 0, 1);
    STAGEX(ldsB, sB[0][0], sB[1][0], 0, 1);
    VMW4;
    __builtin_amdgcn_s_barrier();

#pragma unroll 1
    for (int i = 0; i < NIT; ++i) {
        const int t1 = 2 * i + 1;
        QUAD(0,
             STAGEX(ldsA, sA[0][1], sA[1][1], 1, t1),
             STAGEX(ldsB, sB[0][1], sB[1][1], 1, t1),
             STAGEX(ldsA, sA[0][0], sA[1][0], 0, t1 + 1),
             STAGEX(ldsB, sB[0][0], sB[1][0], 0, t1 + 1));
        QUAD(1,
             STAGEX(ldsA, sA[0][1], sA[1][1], 1, t1 + 1),
             STAGEX(ldsB, sB[0][1], sB[1][1], 1, t1 + 1),
             STAGEX(ldsA, sA[0][0], sA[1][0], 0, t1 + 2),
             STAGEX(ldsB, sB[0][0], sB[1][0], 0, t1 + 2));
    }

    // epilogue: silu(g)*u -> H
    const int hrow0 = offs[e] + tile * 256;
#pragma unroll
    for (int am = 0; am < 8; ++am)
#pragma unroll
        for (int j = 0; j < 4; ++j) {
            int R = wm * 128 + (am >> 2) * 64 + (am & 3) * 16 + lk * 4 + j;
            if (tile * 256 + R < ne) {
#pragma unroll
                for (int ch = 0; ch < 2; ++ch) {
                    float g = acc[am][ch * 2 + 0][j];
                    float u = acc[am][ch * 2 + 1][j];
                    float hv = (g / (1.f + expf(-g))) * u;
                    int brb = by * 256 + wn * 64 + ch * 32 + lr;
                    int hcol = cb + ((brb >> 5) << 4) + (brb & 15);
                    H[(size_t)(hrow0 + R) * DI + hcol] = bf16_rn(hv);
                }
            }
        }
}

// ---------------------------------------------------------------------------
// Down GEMM, 8-phase. 256 H-rows x 256 out-cols, K-split=2. Weighted scatter.
// ---------------------------------------------------------------------------
__global__ __launch_bounds__(512, 2) void down9(
    const unsigned short* __restrict__ dwb,   // [NE][DM][DI] bf16
    const int* __restrict__ counts, const int* __restrict__ offs,
    const int* __restrict__ tiles2, const int* __restrict__ tok_list,
    const float* __restrict__ w_list,
    const unsigned short* __restrict__ H,
    float* __restrict__ out)
{
    const int tx = ((blockIdx.x & 7) * 9) + (blockIdx.x >> 3);  // XCD cluster
    const int pk = tiles2[tx];
    if (pk < 0) return;
    const int e = pk >> 16, tile = pk & 0xffff;
    const int ne = counts[e];
    const int by = blockIdx.y >> 1;            // 0..3 (256-col group of DM)
    const int kq = blockIdx.y & 1;             // K-split half
    const int tid = threadIdx.x, lane = tid & 63, w = tid >> 6;
    const int lr = lane & 15, lk = lane >> 4;
    const int wm = w >> 2, wn = w & 3;
    const int xsw = (lr & 7) << 4;
    const int NKT = (DI / 2) / 64;             // 32
    const int NIT = NKT / 2;                   // 16
    const int kbase = kq * (DI / 2);

    __shared__ __align__(16) unsigned short ldsA[2][2][8192];
    __shared__ __align__(16) unsigned short ldsB[2][2][8192];

    const int hrow0 = offs[e] + tile * 256;
    const unsigned short* sA[2][2];
    const unsigned short* sB[2][2];
#pragma unroll
    for (int q = 0; q < 2; ++q)
#pragma unroll
        for (int h = 0; h < 2; ++h) {
            int bi = q * 8 + w;
            int l8 = bi * 8 + (lane >> 3);
            int scol = (((lane & 7) ^ (l8 & 7)) << 3);
            int R = ((l8 >> 6) << 7) | (h << 6) | (l8 & 63);
            sA[q][h] = H + (size_t)(hrow0 + R) * DI + kbase + scol;  // pad rows finite
            int cc = ((l8 >> 5) << 6) | (h << 5) | (l8 & 31);
            sB[q][h] = dwb + ((size_t)e * DM + by * 256 + cc) * DI + kbase + scol;
        }

    f32x4 acc[8][4];
#pragma unroll
    for (int m = 0; m < 8; ++m)
#pragma unroll
        for (int n = 0; n < 4; ++n) acc[m][n] = (f32x4)0.f;

    bf16x8 ar[4][2], b0r[2][2], b1r[2][2];

    STAGEX(ldsA, sA[0][0], sA[1][0], 0, 0);
    STAGEX(ldsB, sB[0][0], sB[1][0], 0, 0);
    STAGEX(ldsA, sA[0][1], sA[1][1], 1, 0);
    STAGEX(ldsB, sB[0][1], sB[1][1], 1, 0);
    STAGEX(ldsA, sA[0][0], sA[1][0], 0, 1);
    STAGEX(ldsB, sB[0][0], sB[1][0], 0, 1);
    VMW4;
    __builtin_amdgcn_s_barrier();

#pragma unroll 1
    for (int i = 0; i < NIT; ++i) {
        const int t1 = 2 * i + 1;
        QUAD(0,
             STAGEX(ldsA, sA[0][1], sA[1][1], 1, t1),
             STAGEX(ldsB, sB[0][1], sB[1][1], 1, t1),
             STAGEX(ldsA, sA[0][0], sA[1][0], 0, t1 + 1),
             STAGEX(ldsB, sB[0][0], sB[1][0], 0, t1 + 1));
        QUAD(1,
             STAGEX(ldsA, sA[0][1], sA[1][1], 1, t1 + 1),
             STAGEX(ldsB, sB[0][1], sB[1][1], 1, t1 + 1),
             STAGEX(ldsA, sA[0][0], sA[1][0], 0, t1 + 2),
             STAGEX(ldsB, sB[0][0], sB[1][0], 0, t1 + 2));
    }

    // epilogue: weighted atomic scatter
#pragma unroll
    for (int am = 0; am < 8; ++am)
#pragma unroll
        for (int j = 0; j < 4; ++j) {
            int R = wm * 128 + (am >> 2) * 64 + (am & 3) * 16 + lk * 4 + j;
            int grow = tile * 256 + R;
            if (grow < ne) {
                int t = tok_list[e * MAXPE + grow];
                float wgt = w_list[e * MAXPE + grow];
#pragma unroll
                for (int an = 0; an < 4; ++an) {
                    int c = by * 256 + wn * 64 + (an >> 1) * 32 + (an & 1) * 16 + lr;
                    atomicAdd(&out[(size_t)t * DM + c], wgt * acc[am][an][j]);
                }
            }
        }
}

// ---------------------------------------------------------------------------
extern "C" void kernel_launch(void* const* d_in, const int* in_sizes, int n_in,
                              void* d_out, int out_size, void* d_ws, size_t ws_size,
                              hipStream_t stream) {
    const float* x = (const float*)d_in[0];
    const float* router_w = (const float*)d_in[1];
    const float* router_b = (const float*)d_in[2];
    const float* gate_w = (const float*)d_in[3];
    const float* up_w = (const float*)d_in[4];
    const float* down_w = (const float*)d_in[5];
    float* out = (float*)d_out;

    char* ws = (char*)d_ws;
    int* counts = (int*)ws;                              // +0
    int* offs = (int*)(ws + 64);                         // +64
    int* tiles2 = (int*)(ws + 128);                      // 72 ints
    int* tok_list = (int*)(ws + 512);
    float* w_list = (float*)(ws + 512 + (size_t)NE * MAXPE * 4);
    size_t off = 512 + (size_t)NE * MAXPE * 8;
    off = (off + 255) & ~(size_t)255;

    unsigned short* xb = (unsigned short*)(ws + off);  off += (size_t)TOK * DM * 2;
    unsigned short* dwb = (unsigned short*)(ws + off); off += (size_t)NE * DM * DI * 2;
    unsigned short* H = (unsigned short*)(ws + off);   off += (size_t)(2 * TOK + 256) * DI * 2;

    int CHC = 128;
    for (int c = 2048; c >= 128; c >>= 1)
        if (off + (size_t)2 * NE * c * DM * 2 <= ws_size) { CHC = c; break; }
    unsigned short* gwb = (unsigned short*)(ws + off);
    unsigned short* uwb = gwb + (size_t)NE * CHC * DM;

    hipMemsetAsync(out, 0, (size_t)out_size * sizeof(float), stream);
    hipMemsetAsync(counts, 0, NE * sizeof(int), stream);

    router_kernel<<<TOK / 4, 256, 0, stream>>>(x, router_w, router_b,
                                               counts, tok_list, w_list);
    scan_kernel<<<1, 64, 0, stream>>>(counts, offs, tiles2);

    conv_kernel<<<(TOK * DM) / 2048, 256, 0, stream>>>(
        x, xb, (long)TOK * DM, 23, 0);
    conv_kernel<<<(int)(((long)NE * DM * DI) / 2048), 256, 0, stream>>>(
        down_w, dwb, (long)NE * DM * DI, 25, 0);

    const int sh = 10 + __builtin_ctz((unsigned)CHC);   // log2(CHC*DM)
    for (int cb = 0; cb < DI; cb += CHC) {
        long tot = (long)NE * CHC * DM;
        conv_kernel<<<(int)(tot / 2048), 256, 0, stream>>>(
            gate_w + (size_t)cb * DM, gwb, tot, sh, (long)DI * DM);
        conv_kernel<<<(int)(tot / 2048), 256, 0, stream>>>(
            up_w + (size_t)cb * DM, uwb, tot, sh, (long)DI * DM);
        gateup9<<<dim3(NT2, 2 * CHC / 256), 512, 0, stream>>>(
            xb, gwb, uwb, counts, offs, tiles2, tok_list, H, cb, CHC);
    }
    down9<<<dim3(NT2, 8), 512, 0, stream>>>(
        dwb, counts, offs, tiles2, tok_list, w_list, H, out);
}